// Round 1
// baseline (341.340 us; speedup 1.0000x reference)
//
#include <hip/hip_runtime.h>

// Unfold: x[B=32, C=64, H=64, W=64] fp32, KH=KW=3, stride=1
// out[b][c*9 + i*3 + j][ho*62 + wo] = x[b][c][ho+i][wo+j]
// out shape [32, 576, 3844]; L=3844 = 4*961 -> float4 stores, rows 16B-aligned.

#define B 32
#define C 64
#define H 64
#define W 64
#define KH 3
#define KW 3
#define HO 62
#define WO 62
#define L (HO * WO)      // 3844
#define L4 (L / 4)       // 961
#define K (C * KH * KW)  // 576

__global__ __launch_bounds__(256) void unfold_kernel(
    const float* __restrict__ x, float* __restrict__ out) {
    const int idx4 = blockIdx.x * blockDim.x + threadIdx.x;  // 0..L4-1 (some OOB)
    const int k    = blockIdx.y;                             // 0..575
    const int b    = blockIdx.z;                             // 0..31
    if (idx4 >= L4) return;

    // Decompose k -> (c, i, j); block-uniform values.
    const int c = k / (KH * KW);
    const int p = k - c * (KH * KW);
    const int i = p / KW;
    const int j = p - i * KW;

    const int l0 = idx4 * 4;
    int ho = l0 / WO;
    int wo = l0 - ho * WO;

    // x[b][c][ho+i][wo+j] = x[(b*C + c)*H*W + (ho+i)*W + (wo+j)]
    const float* __restrict__ xrow = x + ((size_t)(b * C + c)) * (H * W) + (size_t)i * W + j;

    float4 v;
    float r[4];
#pragma unroll
    for (int q = 0; q < 4; ++q) {
        r[q] = xrow[ho * W + wo];
        ++wo;
        if (wo == WO) { wo = 0; ++ho; }
    }
    v.x = r[0]; v.y = r[1]; v.z = r[2]; v.w = r[3];

    // out row (b,k) starts at (b*K + k)*L floats; L*4 bytes = 15376 = 961*16 -> 16B aligned.
    float4* __restrict__ out4 = (float4*)out;
    out4[(size_t)(b * K + k) * L4 + idx4] = v;
}

extern "C" void kernel_launch(void* const* d_in, const int* in_sizes, int n_in,
                              void* d_out, int out_size, void* d_ws, size_t ws_size,
                              hipStream_t stream) {
    const float* x = (const float*)d_in[0];
    float* out = (float*)d_out;

    dim3 block(256, 1, 1);
    dim3 grid((L4 + 255) / 256, K, B);  // (4, 576, 32)
    unfold_kernel<<<grid, block, 0, stream>>>(x, out);
}

// Round 2
// 313.821 us; speedup vs baseline: 1.0877x; 1.0877x over previous
//
#include <hip/hip_runtime.h>

// Unfold: x[B=32, C=64, H=64, W=64] fp32, KH=KW=3, stride=1
// out[b][c*9 + i*3 + j][ho*62 + wo] = x[b][c][ho+i][wo+j]; out [32, 576, 3844].
//
// One block per (b,c) channel. Stage the 16 KB channel in LDS (read from HBM
// exactly once), then write all 9 output rows as coalesced float4 streams,
// ~34 float4 stores per thread. LDS uses a +1-pad-per-32-floats swizzle
// (idx -> idx + (idx>>5)) so stride-4-float accesses are bank-conflict-free.

#define B 32
#define C 64
#define H 64
#define W 64
#define HO 62
#define WO 62
#define L (HO * WO)   // 3844
#define L4 (L / 4)    // 961
#define KK 9          // KH*KW

__device__ __forceinline__ int sw(int p) { return p + (p >> 5); }

__global__ __launch_bounds__(256) void unfold_kernel(
    const float* __restrict__ x, float* __restrict__ out) {
    __shared__ float tile[H * W + (H * W) / 32];  // 4096 + 128 floats = 16.9 KB

    const int c   = blockIdx.x;   // 0..63
    const int b   = blockIdx.y;   // 0..31
    const int tid = threadIdx.x;  // 0..255

    // ---- Stage channel (b,c): 4096 floats = 1024 float4, coalesced. ----
    const float4* __restrict__ src =
        (const float4*)(x + (((size_t)(b * C + c)) << 12));
#pragma unroll
    for (int r = 0; r < 4; ++r) {
        const int p4 = tid + r * 256;  // 0..1023
        float4 v = src[p4];
        const int p = p4 * 4;
        tile[sw(p)]     = v.x;   // stride-4 writes: conflict-free under swizzle
        tile[sw(p + 1)] = v.y;
        tile[sw(p + 2)] = v.z;
        tile[sw(p + 3)] = v.w;
    }
    __syncthreads();

    // ---- Emit 9 output rows for this (b,c). ----
    float4* __restrict__ dst =
        (float4*)out + (size_t)(b * C + c) * KK * L4;

#pragma unroll
    for (int k = 0; k < KK; ++k) {
        const int i = k / 3;            // constants after unroll
        const int j = k - i * 3;
        const int base = i * W + j;
        for (int t = tid; t < L4; t += 256) {
            const int l0 = t * 4;
            int ho = l0 / WO;           // magic-mul division
            int wo = l0 - ho * WO;
            int addr = base + ho * W + wo;
            float r[4];
#pragma unroll
            for (int q = 0; q < 4; ++q) {
                r[q] = tile[sw(addr)];
                ++addr;
                ++wo;
                if (wo == WO) { wo = 0; addr += (W - WO); }  // wrap to next row
            }
            float4 v;
            v.x = r[0]; v.y = r[1]; v.z = r[2]; v.w = r[3];
            dst[k * L4 + t] = v;        // coalesced dwordx4 stream
        }
    }
}

extern "C" void kernel_launch(void* const* d_in, const int* in_sizes, int n_in,
                              void* d_out, int out_size, void* d_ws, size_t ws_size,
                              hipStream_t stream) {
    const float* x = (const float*)d_in[0];
    float* out = (float*)d_out;

    dim3 block(256, 1, 1);
    dim3 grid(C, B, 1);  // one block per (b,c) channel: 2048 blocks
    unfold_kernel<<<grid, block, 0, stream>>>(x, out);
}